// Round 3
// baseline (570.819 us; speedup 1.0000x reference)
//
#include <hip/hip_runtime.h>
#include <stdint.h>

#define D_MODEL 2048
#define N_EXP   64
#define TOKS    16                  // tokens per block (grid 2048)
#define WAVES   4                   // 256 threads
#define KW      (D_MODEL / WAVES)   // 512 k per wave (private K-split)
#define KQW     (KW / 4)            // 128 float4-quads per wave

// ---- W repack: Wq2[kq][j][eg] = float4{ W[16j+eg][4kq+i] }, 512 KB in d_ws -
// float index o = ((kq*64 + 16*j + eg) << 2) + i
__global__ void make_Wq2(const float* __restrict__ W, float* __restrict__ Wq2) {
    int o  = blockIdx.x * 256 + threadIdx.x;
    int i  = o & 3;
    int eg = (o >> 2) & 15;
    int j  = (o >> 6) & 3;
    int kq = o >> 8;
    Wq2[o] = W[(16 * j + eg) * D_MODEL + 4 * kq + i];
}

__global__ __launch_bounds__(256, 4)
void router_d(const float* __restrict__ x, const float4* __restrict__ Wq2,
              const float* __restrict__ bias, float* __restrict__ out, int n_tokens)
{
    __shared__ float red[2][TOKS * 65];   // reduction overlay only (pad 65)
    const int tid  = threadIdx.x;
    const int lane = tid & 63;
    const int wv   = tid >> 6;
    const int tg   = lane >> 4;       // token group 0..3: tokens t = 4*tt + tg
    const int eg   = lane & 15;       // expert group 0..15: experts e = 16*j + eg
    const int tok0 = blockIdx.x * TOKS;
    const int kq0  = wv * KQW;        // this wave's private K-slice (float4 units)

    float acc[4][4];
    #pragma unroll
    for (int tt = 0; tt < 4; ++tt)
        #pragma unroll
        for (int j = 0; j < 4; ++j) acc[tt][j] = 0.f;

    // x rows as float4 streams; 16 eg-lanes broadcast-read the same address,
    // consecutive q hit the same 128B line 8x -> L1-served after first touch.
    const float4* xr[4];
    #pragma unroll
    for (int tt = 0; tt < 4; ++tt)
        xr[tt] = (const float4*)(x + (size_t)(tok0 + 4 * tt + tg) * D_MODEL);

    // flat load stream, no waitcnt barriers: compiler pipelines across unroll
    #pragma unroll 4
    for (int q = 0; q < KQW; ++q) {
        const int kq = kq0 + q;
        float4 xv[4];
        #pragma unroll
        for (int tt = 0; tt < 4; ++tt) xv[tt] = xr[tt][kq];
        const float4* wp = Wq2 + (size_t)kq * 64 + eg;
        #pragma unroll
        for (int j = 0; j < 4; ++j) {
            const float4 w4 = wp[16 * j];                // 256B coalesced, L2-resident
            #pragma unroll
            for (int tt = 0; tt < 4; ++tt) {
                acc[tt][j] = fmaf(w4.x, xv[tt].x, acc[tt][j]);
                acc[tt][j] = fmaf(w4.y, xv[tt].y, acc[tt][j]);
                acc[tt][j] = fmaf(w4.z, xv[tt].z, acc[tt][j]);
                acc[tt][j] = fmaf(w4.w, xv[tt].w, acc[tt][j]);
            }
        }
    }

    // ---- cross-wave reduction: 4 K-partials -> wave 0 -----------------------
    __syncthreads();
    if (wv >= 2) {
        float* R = red[wv - 2];
        #pragma unroll
        for (int tt = 0; tt < 4; ++tt)
            #pragma unroll
            for (int j = 0; j < 4; ++j)
                R[(4 * tt + tg) * 65 + 16 * j + eg] = acc[tt][j];
    }
    __syncthreads();
    if (wv < 2) {
        const float* R = red[wv];
        #pragma unroll
        for (int tt = 0; tt < 4; ++tt)
            #pragma unroll
            for (int j = 0; j < 4; ++j)
                acc[tt][j] += R[(4 * tt + tg) * 65 + 16 * j + eg];
    }
    __syncthreads();
    if (wv == 1) {
        float* R = red[0];
        #pragma unroll
        for (int tt = 0; tt < 4; ++tt)
            #pragma unroll
            for (int j = 0; j < 4; ++j)
                R[(4 * tt + tg) * 65 + 16 * j + eg] = acc[tt][j];
    }
    __syncthreads();

    // ---- epilogue: bias + top-2 + softmax, wave 0 ---------------------------
    if (wv == 0) {
        const float* R = red[0];
        float bj[4];
        #pragma unroll
        for (int j = 0; j < 4; ++j) bj[j] = bias[16 * j + eg];
        float* ow = out + 2 * (size_t)n_tokens;

        #pragma unroll
        for (int tt = 0; tt < 4; ++tt) {
            float v[4];
            #pragma unroll
            for (int j = 0; j < 4; ++j)
                v[j] = acc[tt][j] + R[(4 * tt + tg) * 65 + 16 * j + eg] + bj[j];
            // local top-2 over this lane's 4 experts (e = 16j+eg ascending)
            float v1 = v[0]; int i1 = eg;
            float v2 = -3.4e38f; int i2 = 1 << 20;
            #pragma unroll
            for (int j = 1; j < 4; ++j) {
                const int e = 16 * j + eg;
                if (v[j] > v1)      { v2 = v1; i2 = i1; v1 = v[j]; i1 = e; }
                else if (v[j] > v2) { v2 = v[j]; i2 = e; }
            }
            // butterfly merge across the 16 eg-lanes (tie: lower index)
            #pragma unroll
            for (int m = 1; m < 16; m <<= 1) {
                float b1 = __shfl_xor(v1, m, 64); int j1 = __shfl_xor(i1, m, 64);
                float b2 = __shfl_xor(v2, m, 64); int j2 = __shfl_xor(i2, m, 64);
                bool aw = (v1 > b1) || (v1 == b1 && i1 < j1);
                float lw_v = aw ? b1 : v1;  int lw_i = aw ? j1 : i1;
                float ws_v = aw ? v2 : b2;  int ws_i = aw ? i2 : j2;
                float nv1  = aw ? v1 : b1;  int ni1  = aw ? i1 : j1;
                bool sw = (lw_v > ws_v) || (lw_v == ws_v && lw_i < ws_i);
                v1 = nv1;               i1 = ni1;
                v2 = sw ? lw_v : ws_v;  i2 = sw ? lw_i : ws_i;
            }
            // softmax denominator over all 64 experts
            float ssum = 0.f;
            #pragma unroll
            for (int j = 0; j < 4; ++j) ssum += __expf(v[j] - v1);
            #pragma unroll
            for (int m = 1; m < 16; m <<= 1) ssum += __shfl_xor(ssum, m, 64);
            const float inv = 1.0f / ssum;
            const float w1  = inv;
            const float w2  = __expf(v2 - v1) * inv;

            if (eg == tt) {
                const int g = tok0 + 4 * tt + tg;
                float2 fi; fi.x = (float)i1; fi.y = (float)i2;
                ((float2*)out)[g] = fi;
                float2 fw; fw.x = w1; fw.y = w2;
                ((float2*)ow)[g] = fw;
            }
        }
    }
}

extern "C" void kernel_launch(void* const* d_in, const int* in_sizes, int n_in,
                              void* d_out, int out_size, void* d_ws, size_t ws_size,
                              hipStream_t stream) {
    const float* x = (const float*)d_in[0];
    const float* W = (const float*)d_in[1];
    const float* b = (const float*)d_in[2];
    float* out = (float*)d_out;
    float* Wq2 = (float*)d_ws;                       // 512 KB scratch
    const int n_tokens = in_sizes[0] / D_MODEL;      // 32768

    make_Wq2<<<(D_MODEL * N_EXP) / 256, 256, 0, stream>>>(W, Wq2);
    router_d<<<n_tokens / TOKS, 256, 0, stream>>>(x, (const float4*)Wq2, b, out, n_tokens);
}

// Round 4
// 479.444 us; speedup vs baseline: 1.1906x; 1.1906x over previous
//
#include <hip/hip_runtime.h>
#include <stdint.h>

#define D_MODEL 2048
#define N_EXP   64
#define TOKS    64                 // tokens per block (grid 512 = 2 blocks/CU)
#define NCHUNK  32                 // K-chunks of 64 k
#define CQ      16                 // float4-quads per chunk
#define QW      4                  // quads per wave per chunk (4-wave K-split)

// ---- W repack (pre-swizzled for linear global_load_lds + conflict-free read):
// Wq3[c][e][col] (float4) = W[e][4*(c*16 + qL) .. +3], qL = (col&8)|((col&7)^(e&7))
__global__ void make_Wq3(const float* __restrict__ W, float* __restrict__ Wq3) {
    int o   = blockIdx.x * 256 + threadIdx.x;     // float index, 131072 total
    int i   = o & 3;
    int col = (o >> 2) & 15;
    int e   = (o >> 6) & 63;
    int c   = o >> 12;
    int qL  = (col & 8) | ((col & 7) ^ (e & 7));
    Wq3[o]  = W[e * D_MODEL + 4 * (c * 16 + qL) + i];
}

union SMemU {
    struct { float4 xs[2][TOKS * CQ]; float4 ws[2][N_EXP * CQ]; } st;  // 32KB + 32KB
    float red[2][TOKS * 65];                                           // 33.3KB overlay
};

__global__ __launch_bounds__(256, 2)
void router_d(const float* __restrict__ x, const float4* __restrict__ Wq3,
              const float* __restrict__ bias, float* __restrict__ out, int n_tokens)
{
    __shared__ SMemU sm;
    const int tid  = threadIdx.x;
    const int lane = tid & 63;
    const int wv   = tid >> 6;
    const int tg   = lane >> 3;       // token group 0..7: tokens t = 8*tt + tg
    const int eg   = lane & 7;        // expert group 0..7: experts e = 8*j + eg
    const int tok0 = blockIdx.x * TOKS;

    // staging lane decomposition (shared cooperative, 16 x 1KB instrs per chunk,
    // 4 per wave): instr i2 covers tokens 4*i2..4*i2+3, 16 quads each.
    const int sl_t4 = lane >> 4;      // 0..3 token-sub
    const int sl_c  = lane & 15;      // 0..15 stored col

    float acc[8][8];
    #pragma unroll
    for (int tt = 0; tt < 8; ++tt)
        #pragma unroll
        for (int j = 0; j < 8; ++j) acc[tt][j] = 0.f;

    auto stage_x = [&](int c, float4* xb) {
        #pragma unroll
        for (int it = 0; it < 4; ++it) {
            const int i2 = wv * 4 + it;
            const int t  = i2 * 4 + sl_t4;
            const int qL = (sl_c & 8) | ((sl_c & 7) ^ (t & 7));   // inverse swizzle
            const float* gp = x + (size_t)(tok0 + t) * D_MODEL + c * 64 + 4 * qL;
            float4* lp = xb + i2 * 64;                             // wave-uniform base
            __builtin_amdgcn_global_load_lds(
                (const __attribute__((address_space(1))) void*)gp,
                (__attribute__((address_space(3))) void*)lp, 16, 0, 0);
        }
    };
    auto stage_w = [&](int c, float4* wb) {
        #pragma unroll
        for (int iw = 0; iw < 4; ++iw) {
            const int i2 = wv * 4 + iw;
            const float4* gp = Wq3 + (size_t)c * 1024 + i2 * 64 + lane;  // pre-swizzled
            float4* lp = wb + i2 * 64;
            __builtin_amdgcn_global_load_lds(
                (const __attribute__((address_space(1))) void*)gp,
                (__attribute__((address_space(3))) void*)lp, 16, 0, 0);
        }
    };

    stage_x(0, sm.st.xs[0]);
    stage_w(0, sm.st.ws[0]);

    for (int c = 0; c < NCHUNK; ++c) {
        asm volatile("s_waitcnt vmcnt(0)" ::: "memory");   // chunk c landed (this wave)
        __syncthreads();                                   // published to all waves
        if (c + 1 < NCHUNK) {                              // safe: all waves past c-1 reads
            stage_x(c + 1, sm.st.xs[(c + 1) & 1]);
            stage_w(c + 1, sm.st.ws[(c + 1) & 1]);
        }
        const float4* xb = sm.st.xs[c & 1];
        const float4* wb = sm.st.ws[c & 1];
        // ---- compute: 4 q x (8 x-ds_read + 8 W-ds_read + 256 FMA) -----------
        #pragma unroll
        for (int q = 0; q < QW; ++q) {
            const int qh   = wv * QW + q;                  // logical quad 0..15
            const int xcol = (qh & 8) | ((qh & 7) ^ tg);   // conflict-free via XOR
            float4 xv[8];
            #pragma unroll
            for (int tt = 0; tt < 8; ++tt)
                xv[tt] = xb[(8 * tt + tg) * CQ + xcol];
            #pragma unroll
            for (int j = 0; j < 8; ++j) {
                const int e    = 8 * j + eg;
                const int wcol = (qh & 8) | ((qh & 7) ^ eg);
                const float4 w4 = wb[e * CQ + wcol];
                #pragma unroll
                for (int tt = 0; tt < 8; ++tt) {
                    acc[tt][j] = fmaf(w4.x, xv[tt].x, acc[tt][j]);
                    acc[tt][j] = fmaf(w4.y, xv[tt].y, acc[tt][j]);
                    acc[tt][j] = fmaf(w4.z, xv[tt].z, acc[tt][j]);
                    acc[tt][j] = fmaf(w4.w, xv[tt].w, acc[tt][j]);
                }
            }
        }
    }

    // ---- cross-wave reduction: 4 K-partials -> wave 0 (overlay over staging) -
    __syncthreads();
    if (wv >= 2) {
        float* R = sm.red[wv - 2];
        #pragma unroll
        for (int tt = 0; tt < 8; ++tt)
            #pragma unroll
            for (int j = 0; j < 8; ++j)
                R[(8 * tt + tg) * 65 + 8 * j + eg] = acc[tt][j];
    }
    __syncthreads();
    if (wv < 2) {
        const float* R = sm.red[wv];
        #pragma unroll
        for (int tt = 0; tt < 8; ++tt)
            #pragma unroll
            for (int j = 0; j < 8; ++j)
                acc[tt][j] += R[(8 * tt + tg) * 65 + 8 * j + eg];
    }
    __syncthreads();
    if (wv == 1) {
        float* R = sm.red[0];
        #pragma unroll
        for (int tt = 0; tt < 8; ++tt)
            #pragma unroll
            for (int j = 0; j < 8; ++j)
                R[(8 * tt + tg) * 65 + 8 * j + eg] = acc[tt][j];
    }
    __syncthreads();

    // ---- epilogue: bias + top-2 + softmax, wave 0 ---------------------------
    if (wv == 0) {
        const float* R = sm.red[0];
        float bj[8];
        #pragma unroll
        for (int j = 0; j < 8; ++j) bj[j] = bias[8 * j + eg];
        float* ow = out + 2 * (size_t)n_tokens;

        #pragma unroll
        for (int tt = 0; tt < 8; ++tt) {
            float v[8];
            #pragma unroll
            for (int j = 0; j < 8; ++j)
                v[j] = acc[tt][j] + R[(8 * tt + tg) * 65 + 8 * j + eg] + bj[j];
            // local top-2 over this lane's 8 experts (e = 8j+eg ascending)
            float v1 = v[0]; int i1 = eg;
            float v2 = -3.4e38f; int i2 = 1 << 20;
            #pragma unroll
            for (int j = 1; j < 8; ++j) {
                const int e = 8 * j + eg;
                if (v[j] > v1)      { v2 = v1; i2 = i1; v1 = v[j]; i1 = e; }
                else if (v[j] > v2) { v2 = v[j]; i2 = e; }
            }
            // butterfly merge across the 8 eg-lanes (tie: lower index)
            #pragma unroll
            for (int m = 1; m < 8; m <<= 1) {
                float b1 = __shfl_xor(v1, m, 64); int j1 = __shfl_xor(i1, m, 64);
                float b2 = __shfl_xor(v2, m, 64); int j2 = __shfl_xor(i2, m, 64);
                bool aw = (v1 > b1) || (v1 == b1 && i1 < j1);
                float lw_v = aw ? b1 : v1;  int lw_i = aw ? j1 : i1;
                float ws_v = aw ? v2 : b2;  int ws_i = aw ? i2 : j2;
                float nv1  = aw ? v1 : b1;  int ni1  = aw ? i1 : j1;
                bool sw = (lw_v > ws_v) || (lw_v == ws_v && lw_i < ws_i);
                v1 = nv1;               i1 = ni1;
                v2 = sw ? lw_v : ws_v;  i2 = sw ? lw_i : ws_i;
            }
            // softmax denominator over all 64 experts
            float ssum = 0.f;
            #pragma unroll
            for (int j = 0; j < 8; ++j) ssum += __expf(v[j] - v1);
            #pragma unroll
            for (int m = 1; m < 8; m <<= 1) ssum += __shfl_xor(ssum, m, 64);
            const float inv = 1.0f / ssum;
            const float w1  = inv;
            const float w2  = __expf(v2 - v1) * inv;

            if (eg == tt) {
                const int g = tok0 + 8 * tt + tg;
                float2 fi; fi.x = (float)i1; fi.y = (float)i2;
                ((float2*)out)[g] = fi;
                float2 fw; fw.x = w1; fw.y = w2;
                ((float2*)ow)[g] = fw;
            }
        }
    }
}

extern "C" void kernel_launch(void* const* d_in, const int* in_sizes, int n_in,
                              void* d_out, int out_size, void* d_ws, size_t ws_size,
                              hipStream_t stream) {
    const float* x = (const float*)d_in[0];
    const float* W = (const float*)d_in[1];
    const float* b = (const float*)d_in[2];
    float* out = (float*)d_out;
    float* Wq3 = (float*)d_ws;                       // 512 KB scratch
    const int n_tokens = in_sizes[0] / D_MODEL;      // 32768

    make_Wq3<<<(D_MODEL * N_EXP) / 256, 256, 0, stream>>>(W, Wq3);
    router_d<<<n_tokens / TOKS, 256, 0, stream>>>(x, (const float4*)Wq3, b, out, n_tokens);
}

// Round 5
// 411.965 us; speedup vs baseline: 1.3856x; 1.1638x over previous
//
#include <hip/hip_runtime.h>
#include <stdint.h>

#define D_MODEL 2048
#define N_EXP   64
#define TOKS    64                  // tokens per block (grid 512 = 2 blocks/CU)
#define WAVES   4                   // 256 threads, 4-way private K-split
#define KW      (D_MODEL / WAVES)   // 512 k per wave
#define SUBK    16                  // k per sub-chunk (per wave)
#define NSUB    (KW / SUBK)         // 32 sub-chunks
#define SUBQ    4                   // float4-quads per sub-chunk

// ---- W repack: Wq[kq][e] = float4{ W[e][4kq..4kq+3] }, 512 KB in d_ws ------
__global__ void make_Wq(const float* __restrict__ W, float* __restrict__ Wq) {
    int o  = blockIdx.x * 256 + threadIdx.x;   // float index, 131072 total
    int i  = o & 3;
    int e  = (o >> 2) & 63;
    int kq = o >> 8;
    Wq[o] = W[e * D_MODEL + 4 * kq + i];
}

union SMemU {
    // [wave][buf][0=x,1=W][256 f4]: per-wave-private, double-buffered, 64 KB
    float4 st[WAVES][2][2][64 * SUBQ];
    float  red[2][TOKS * 65];               // 33 KB reduction overlay (pad 65)
};

__global__ __launch_bounds__(256, 2)
void router_d(const float* __restrict__ x, const float4* __restrict__ Wq,
              const float* __restrict__ bias, float* __restrict__ out, int n_tokens)
{
    __shared__ SMemU sm;
    const int tid  = threadIdx.x;
    const int lane = tid & 63;
    const int wv   = tid >> 6;
    const int tg   = lane >> 3;       // token group 0..7: tokens t = 8*tt + tg
    const int eg   = lane & 7;        // expert group 0..7: experts e = 8*j + eg
    const int tok0 = blockIdx.x * TOKS;
    const int kw   = wv * KW;         // this wave's k-base
    const int kq0  = wv * (KW / 4);   // this wave's quad-base in Wq

    // staging lane constants: x instr covers 16 tokens x 4 cols (16B each)
    const int sct = lane >> 2;        // token-sub 0..15
    const int scc = lane & 3;         // stored col 0..3
    const int sgc = scc ^ (sct & 3);  // pre-swizzled GLOBAL col; LDS stays linear
    const float*  xrow = x + (size_t)(tok0 + sct) * D_MODEL + 4 * sgc;
    const float4* wrow = Wq + lane;   // W stage: 1 KB contiguous per instr

    float acc[8][8];
    #pragma unroll
    for (int tt = 0; tt < 8; ++tt)
        #pragma unroll
        for (int j = 0; j < 8; ++j) acc[tt][j] = 0.f;

    auto stage = [&](int c, int buf) {
        const int kb = kw + c * SUBK;
        float4* xb = sm.st[wv][buf][0];
        float4* wb = sm.st[wv][buf][1];
        #pragma unroll
        for (int i2 = 0; i2 < 4; ++i2) {   // x: [t][col] rows of 4 f4, swizzled src
            const float* gp = xrow + (size_t)(i2 * 16) * D_MODEL + kb;
            __builtin_amdgcn_global_load_lds(
                (const __attribute__((address_space(1))) void*)gp,
                (__attribute__((address_space(3))) void*)(xb + i2 * 64), 16, 0, 0);
        }
        #pragma unroll
        for (int i2 = 0; i2 < 4; ++i2) {   // W: [kq_local][e], linear
            const float4* gp = wrow + (size_t)(kq0 + c * 4 + i2) * 64;
            __builtin_amdgcn_global_load_lds(
                (const __attribute__((address_space(1))) void*)gp,
                (__attribute__((address_space(3))) void*)(wb + i2 * 64), 16, 0, 0);
        }
    };

    stage(0, 0);                          // prologue: fill pipe

    for (int c = 0; c < NSUB; ++c) {
        if (c + 1 < NSUB) {
            stage(c + 1, (c + 1) & 1);    // keep next chunk's 8 loads in flight
            asm volatile("s_waitcnt vmcnt(8)" ::: "memory");   // chunk c landed
        } else {
            asm volatile("s_waitcnt vmcnt(0)" ::: "memory");
        }
        const float4* xb = sm.st[wv][c & 1][0];
        const float4* wb = sm.st[wv][c & 1][1];
        // ---- compute: 4 q x (8 x-ds_read + 8 W-ds_read + 256 FMA) -----------
        #pragma unroll
        for (int q = 0; q < SUBQ; ++q) {
            float4 xv[8];
            #pragma unroll
            for (int tt = 0; tt < 8; ++tt)
                xv[tt] = xb[(8 * tt + tg) * 4 + (q ^ (tg & 3))];  // 2-way-free banks
            #pragma unroll
            for (int j = 0; j < 8; ++j) {
                const float4 w4 = wb[q * 64 + 8 * j + eg];        // conflict-free bcast
                #pragma unroll
                for (int tt = 0; tt < 8; ++tt) {
                    acc[tt][j] = fmaf(w4.x, xv[tt].x, acc[tt][j]);
                    acc[tt][j] = fmaf(w4.y, xv[tt].y, acc[tt][j]);
                    acc[tt][j] = fmaf(w4.z, xv[tt].z, acc[tt][j]);
                    acc[tt][j] = fmaf(w4.w, xv[tt].w, acc[tt][j]);
                }
            }
        }
    }

    // ---- cross-wave reduction: 4 K-partials -> wave 0 (overlay over staging) -
    __syncthreads();
    if (wv >= 2) {
        float* R = sm.red[wv - 2];
        #pragma unroll
        for (int tt = 0; tt < 8; ++tt)
            #pragma unroll
            for (int j = 0; j < 8; ++j)
                R[(8 * tt + tg) * 65 + 8 * j + eg] = acc[tt][j];
    }
    __syncthreads();
    if (wv < 2) {
        const float* R = sm.red[wv];
        #pragma unroll
        for (int tt = 0; tt < 8; ++tt)
            #pragma unroll
            for (int j = 0; j < 8; ++j)
                acc[tt][j] += R[(8 * tt + tg) * 65 + 8 * j + eg];
    }
    __syncthreads();
    if (wv == 1) {
        float* R = sm.red[0];
        #pragma unroll
        for (int tt = 0; tt < 8; ++tt)
            #pragma unroll
            for (int j = 0; j < 8; ++j)
                R[(8 * tt + tg) * 65 + 8 * j + eg] = acc[tt][j];
    }
    __syncthreads();

    // ---- epilogue: bias + top-2 + softmax, wave 0 ---------------------------
    if (wv == 0) {
        const float* R = sm.red[0];
        float bj[8];
        #pragma unroll
        for (int j = 0; j < 8; ++j) bj[j] = bias[8 * j + eg];
        float* ow = out + 2 * (size_t)n_tokens;

        #pragma unroll
        for (int tt = 0; tt < 8; ++tt) {
            float v[8];
            #pragma unroll
            for (int j = 0; j < 8; ++j)
                v[j] = acc[tt][j] + R[(8 * tt + tg) * 65 + 8 * j + eg] + bj[j];
            // local top-2 over this lane's 8 experts (e = 8j+eg ascending)
            float v1 = v[0]; int i1 = eg;
            float v2 = -3.4e38f; int i2 = 1 << 20;
            #pragma unroll
            for (int j = 1; j < 8; ++j) {
                const int e = 8 * j + eg;
                if (v[j] > v1)      { v2 = v1; i2 = i1; v1 = v[j]; i1 = e; }
                else if (v[j] > v2) { v2 = v[j]; i2 = e; }
            }
            // butterfly merge across the 8 eg-lanes (tie: lower index)
            #pragma unroll
            for (int m = 1; m < 8; m <<= 1) {
                float b1 = __shfl_xor(v1, m, 64); int j1 = __shfl_xor(i1, m, 64);
                float b2 = __shfl_xor(v2, m, 64); int j2 = __shfl_xor(i2, m, 64);
                bool aw = (v1 > b1) || (v1 == b1 && i1 < j1);
                float lw_v = aw ? b1 : v1;  int lw_i = aw ? j1 : i1;
                float ws_v = aw ? v2 : b2;  int ws_i = aw ? i2 : j2;
                float nv1  = aw ? v1 : b1;  int ni1  = aw ? i1 : j1;
                bool sw = (lw_v > ws_v) || (lw_v == ws_v && lw_i < ws_i);
                v1 = nv1;               i1 = ni1;
                v2 = sw ? lw_v : ws_v;  i2 = sw ? lw_i : ws_i;
            }
            // softmax denominator over all 64 experts
            float ssum = 0.f;
            #pragma unroll
            for (int j = 0; j < 8; ++j) ssum += __expf(v[j] - v1);
            #pragma unroll
            for (int m = 1; m < 8; m <<= 1) ssum += __shfl_xor(ssum, m, 64);
            const float inv = 1.0f / ssum;
            const float w1  = inv;
            const float w2  = __expf(v2 - v1) * inv;

            if (eg == tt) {
                const int g = tok0 + 8 * tt + tg;
                float2 fi; fi.x = (float)i1; fi.y = (float)i2;
                ((float2*)out)[g] = fi;
                float2 fw; fw.x = w1; fw.y = w2;
                ((float2*)ow)[g] = fw;
            }
        }
    }
}

extern "C" void kernel_launch(void* const* d_in, const int* in_sizes, int n_in,
                              void* d_out, int out_size, void* d_ws, size_t ws_size,
                              hipStream_t stream) {
    const float* x = (const float*)d_in[0];
    const float* W = (const float*)d_in[1];
    const float* b = (const float*)d_in[2];
    float* out = (float*)d_out;
    float* Wq = (float*)d_ws;                        // 512 KB scratch
    const int n_tokens = in_sizes[0] / D_MODEL;      // 32768

    make_Wq<<<(D_MODEL * N_EXP) / 256, 256, 0, stream>>>(W, Wq);
    router_d<<<n_tokens / TOKS, 256, 0, stream>>>(x, (const float4*)Wq, b, out, n_tokens);
}